// Round 1
// baseline (1699.984 us; speedup 1.0000x reference)
//
#include <hip/hip_runtime.h>
#include <math.h>

#define NH 8
#define HS 32
#define SD 257
#define SS 256
#define NN 2048
#define BB 4
#define INV_CURV 10.0f
#define RCONST 3.16227766016838f
#define SCALE 0.17677669529663687f
#define EPSF 1e-9f

// ---------------------------------------------------------------------------
// Kernel 1: Lorentz projections. One block per (b,n). 256 threads = (h, s).
// Computes q_space, q_time, k_space, k_time, v_tan (= logmap0 of v).
// ---------------------------------------------------------------------------
__global__ __launch_bounds__(256) void proj_kernel(
    const float* __restrict__ x,
    const float* __restrict__ Wq, const float* __restrict__ bq,
    const float* __restrict__ Wk, const float* __restrict__ bk,
    const float* __restrict__ Wv, const float* __restrict__ bv,
    float* __restrict__ qs, float* __restrict__ qt,
    float* __restrict__ ks, float* __restrict__ kt,
    float* __restrict__ vt)
{
    __shared__ float xl[SD];
    const int bn  = blockIdx.x;          // b*NN + n
    const int tid = threadIdx.x;
    const float* xrow = x + (size_t)bn * SD;
    for (int d = tid; d < SD; d += 256) xl[d] = xrow[d];
    __syncthreads();

    const int h = tid >> 5;
    const int s = tid & 31;
    const int b = bn / NN;
    const int n = bn % NN;
    const size_t tbase   = (size_t)(b * NH + h) * NN + n;
    const size_t outbase = tbase * HS + s;

    // ---- Q ----
    {
        const float* W = Wq + (size_t)h * SD * HS + s;
        float acc = bq[h * HS + s];
        for (int d = 0; d < SD; ++d) acc = fmaf(xl[d], W[(size_t)d * HS], acc);
        float sq = acc * acc;
        #pragma unroll
        for (int off = 16; off > 0; off >>= 1) sq += __shfl_xor(sq, off, 64);
        qs[outbase] = acc;
        if (s == 0) qt[tbase] = sqrtf(INV_CURV + sq);
    }
    // ---- K ----
    {
        const float* W = Wk + (size_t)h * SD * HS + s;
        float acc = bk[h * HS + s];
        for (int d = 0; d < SD; ++d) acc = fmaf(xl[d], W[(size_t)d * HS], acc);
        float sq = acc * acc;
        #pragma unroll
        for (int off = 16; off > 0; off >>= 1) sq += __shfl_xor(sq, off, 64);
        ks[outbase] = acc;
        if (s == 0) kt[tbase] = sqrtf(INV_CURV + sq);
    }
    // ---- V -> v_tan (logmap0) ----
    {
        const float* W = Wv + (size_t)h * SD * HS + s;
        float acc = bv[h * HS + s];
        for (int d = 0; d < SD; ++d) acc = fmaf(xl[d], W[(size_t)d * HS], acc);
        float sq = acc * acc;
        #pragma unroll
        for (int off = 16; off > 0; off >>= 1) sq += __shfl_xor(sq, off, 64);
        const float ns    = sq;                       // ||v_space||^2
        const float vtime = sqrtf(INV_CURV + ns);     // time component
        const float xn    = sqrtf(fmaxf(ns, EPSF));
        const float z     = fmaxf(vtime / RCONST, 1.0f + 1e-7f);
        const float dd    = RCONST * logf(z + sqrtf(z * z - 1.0f)); // R*acosh
        vt[outbase] = (dd / xn) * acc;
    }
}

// ---------------------------------------------------------------------------
// Kernel 2: attention + expmap0 + head concat. One thread per query row.
// Grid = B*NH*NN/256 blocks of 256. Online (flash) softmax, acc[32] in regs.
// k/v row loads are wave-uniform -> L1 broadcast / scalarizable.
// Writes space part of expmap0 directly into cat[b][n][h*32+d].
// ---------------------------------------------------------------------------
__global__ __launch_bounds__(256) void attn_kernel(
    const float* __restrict__ qs, const float* __restrict__ qt,
    const float* __restrict__ ks, const float* __restrict__ kt,
    const float* __restrict__ vt, float* __restrict__ cat)
{
    const int bh = blockIdx.x >> 3;                     // b*NH + h
    const int n  = ((blockIdx.x & 7) << 8) + threadIdx.x;
    const size_t base = ((size_t)bh * NN + n) * HS;

    float q[HS];
    const float4* qp = (const float4*)(qs + base);
    #pragma unroll
    for (int j = 0; j < 8; ++j) {
        float4 f = qp[j];
        q[4*j] = f.x; q[4*j+1] = f.y; q[4*j+2] = f.z; q[4*j+3] = f.w;
    }
    const float qtv = qt[(size_t)bh * NN + n];

    float acc[HS];
    #pragma unroll
    for (int d = 0; d < HS; ++d) acc[d] = 0.0f;
    float mx = -1e30f, sum = 0.0f;

    const float* kbase = ks + (size_t)bh * NN * HS;
    const float* ktb   = kt + (size_t)bh * NN;
    const float* vbase = vt + (size_t)bh * NN * HS;

    for (int m = 0; m < NN; ++m) {
        const float4* kp = (const float4*)(kbase + (size_t)m * HS);
        float sc = -qtv * ktb[m];
        #pragma unroll
        for (int j = 0; j < 8; ++j) {
            float4 f = kp[j];
            sc = fmaf(q[4*j],   f.x, sc);
            sc = fmaf(q[4*j+1], f.y, sc);
            sc = fmaf(q[4*j+2], f.z, sc);
            sc = fmaf(q[4*j+3], f.w, sc);
        }
        sc *= SCALE;
        if (sc > mx) {                       // rare rescale (defer-max style)
            const float corr = __expf(mx - sc);
            mx = sc;
            sum *= corr;
            #pragma unroll
            for (int d = 0; d < HS; ++d) acc[d] *= corr;
        }
        const float p = __expf(sc - mx);
        sum += p;
        const float4* vp = (const float4*)(vbase + (size_t)m * HS);
        #pragma unroll
        for (int j = 0; j < 8; ++j) {
            float4 f = vp[j];
            acc[4*j]   = fmaf(p, f.x, acc[4*j]);
            acc[4*j+1] = fmaf(p, f.y, acc[4*j+1]);
            acc[4*j+2] = fmaf(p, f.z, acc[4*j+2]);
            acc[4*j+3] = fmaf(p, f.w, acc[4*j+3]);
        }
    }

    // normalize + expmap0 (space part only; its time is recomputed later)
    const float inv = 1.0f / sum;
    float un2 = 0.0f;
    #pragma unroll
    for (int d = 0; d < HS; ++d) { acc[d] *= inv; un2 = fmaf(acc[d], acc[d], un2); }
    const float un  = sqrtf(fmaxf(un2, 1e-18f));
    const float fac = RCONST * sinhf(un / RCONST) / un;

    const int b = bh >> 3, h = bh & 7;
    float* cp = cat + ((size_t)(b * NN + n)) * SS + h * HS;
    #pragma unroll
    for (int d = 0; d < HS; ++d) cp[d] = fac * acc[d];
}

// ---------------------------------------------------------------------------
// Kernel 3: output Lorentz FC. One block per (b,n); thread s computes y[s].
// ---------------------------------------------------------------------------
__global__ __launch_bounds__(256) void out_kernel(
    const float* __restrict__ cat, const float* __restrict__ Wo,
    const float* __restrict__ bo, float* __restrict__ out)
{
    __shared__ float row[SS];
    __shared__ float red[8];
    const int bn  = blockIdx.x;
    const int tid = threadIdx.x;

    const float v = cat[(size_t)bn * SS + tid];
    row[tid] = v;
    float sq = v * v;
    #pragma unroll
    for (int off = 32; off > 0; off >>= 1) sq += __shfl_xor(sq, off, 64);
    const int wave = tid >> 6;
    if ((tid & 63) == 0) red[wave] = sq;
    __syncthreads();
    const float ns  = red[0] + red[1] + red[2] + red[3];
    const float tin = sqrtf(INV_CURV + ns);    // time of concatenated point

    float acc = bo[tid] + tin * Wo[tid];       // Wo row 0 is the time row
    const float* Wp = Wo + SS + tid;
    for (int d = 0; d < SS; ++d) acc = fmaf(row[d], Wp[(size_t)d * SS], acc);

    float sq2 = acc * acc;
    #pragma unroll
    for (int off = 32; off > 0; off >>= 1) sq2 += __shfl_xor(sq2, off, 64);
    if ((tid & 63) == 0) red[4 + wave] = sq2;
    __syncthreads();

    float* orow = out + (size_t)bn * SD;
    orow[1 + tid] = acc;
    if (tid == 0) {
        const float ys = red[4] + red[5] + red[6] + red[7];
        orow[0] = sqrtf(INV_CURV + ys);
    }
}

// ---------------------------------------------------------------------------
extern "C" void kernel_launch(void* const* d_in, const int* in_sizes, int n_in,
                              void* d_out, int out_size, void* d_ws, size_t ws_size,
                              hipStream_t stream)
{
    const float* x  = (const float*)d_in[0];
    const float* Wq = (const float*)d_in[1];
    const float* bq = (const float*)d_in[2];
    const float* Wk = (const float*)d_in[3];
    const float* bk = (const float*)d_in[4];
    const float* Wv = (const float*)d_in[5];
    const float* bv = (const float*)d_in[6];
    const float* Wo = (const float*)d_in[7];
    const float* bo = (const float*)d_in[8];
    float* out = (float*)d_out;

    float* ws  = (float*)d_ws;
    float* qs  = ws;                    // B*H*N*32 = 2097152
    float* ks  = ws + 2097152;
    float* vt  = ws + 4194304;
    float* qt  = ws + 6291456;          // B*H*N = 65536
    float* kt  = ws + 6356992;
    float* cat = ws + 6422528;          // B*N*256 = 2097152

    proj_kernel<<<BB * NN, 256, 0, stream>>>(x, Wq, bq, Wk, bk, Wv, bv,
                                             qs, qt, ks, kt, vt);
    attn_kernel<<<BB * NH * NN / 256, 256, 0, stream>>>(qs, qt, ks, kt, vt, cat);
    out_kernel<<<BB * NN, 256, 0, stream>>>(cat, Wo, bo, out);
}

// Round 2
// 251.050 us; speedup vs baseline: 6.7715x; 6.7715x over previous
//
#include <hip/hip_runtime.h>
#include <hip/hip_bf16.h>
#include <math.h>

#define NH 8
#define HS 32
#define SD 257
#define SS 256
#define NN 2048
#define BB 4
#define INV_CURV 10.0f
#define RCONST 3.16227766016837933f
#define SCALE 0.17677669529663687f
#define M0NEG 1.76776695296636881f   // -score_upper_bound = (1/CURV)*SCALE
#define EPSF 1e-9f

typedef unsigned short ushortT;
typedef unsigned int uintT;
typedef __attribute__((ext_vector_type(8))) short bf16x8;
typedef __attribute__((ext_vector_type(4))) float f32x4;

union U4 { uint4 u; bf16x8 h; };

__device__ inline ushortT f2bf(float f) {
    __hip_bfloat16 h = __float2bfloat16(f);
    return *(ushortT*)&h;
}
__device__ inline uintT packbf(float a, float b) {
    return (uintT)f2bf(a) | ((uintT)f2bf(b) << 16);
}

// ---------------------------------------------------------------------------
// Kernel 1: Lorentz projections, 8 tokens per block. 256 threads = (h, s).
// Writes qs,ks bf16 [bh][n][32]; vtT bf16 TRANSPOSED [bh][d][n]; qt,kt fp32.
// ---------------------------------------------------------------------------
__global__ __launch_bounds__(256) void proj_kernel(
    const float* __restrict__ x,
    const float* __restrict__ Wq, const float* __restrict__ bq,
    const float* __restrict__ Wk, const float* __restrict__ bk,
    const float* __restrict__ Wv, const float* __restrict__ bv,
    ushortT* __restrict__ qs, float* __restrict__ qt,
    ushortT* __restrict__ ks, float* __restrict__ kt,
    ushortT* __restrict__ vtT)
{
    __shared__ float xl[8][SD];
    const int bn0 = blockIdx.x * 8;
    const int tid = threadIdx.x;
    #pragma unroll
    for (int j = 0; j < 8; ++j) {
        const float* xr = x + (size_t)(bn0 + j) * SD;
        for (int d = tid; d < SD; d += 256) xl[j][d] = xr[d];
    }
    __syncthreads();

    const int h = tid >> 5, s = tid & 31;
    const int b  = bn0 >> 11;
    const int n0 = bn0 & (NN - 1);
    const int bh = b * NH + h;
    const size_t tb = (size_t)bh * NN + n0;

    // ---- Q ----
    {
        const float* W = Wq + (size_t)h * SD * HS + s;
        float a[8];
        const float bias = bq[h * HS + s];
        #pragma unroll
        for (int j = 0; j < 8; ++j) a[j] = bias;
        for (int d = 0; d < SD; ++d) {
            const float w = W[(size_t)d * HS];
            #pragma unroll
            for (int j = 0; j < 8; ++j) a[j] = fmaf(xl[j][d], w, a[j]);
        }
        #pragma unroll
        for (int j = 0; j < 8; ++j) {
            float sq = a[j] * a[j];
            #pragma unroll
            for (int off = 16; off > 0; off >>= 1) sq += __shfl_xor(sq, off, 64);
            qs[(tb + j) * HS + s] = f2bf(a[j]);
            if (s == 0) qt[tb + j] = sqrtf(INV_CURV + sq);
        }
    }
    // ---- K ----
    {
        const float* W = Wk + (size_t)h * SD * HS + s;
        float a[8];
        const float bias = bk[h * HS + s];
        #pragma unroll
        for (int j = 0; j < 8; ++j) a[j] = bias;
        for (int d = 0; d < SD; ++d) {
            const float w = W[(size_t)d * HS];
            #pragma unroll
            for (int j = 0; j < 8; ++j) a[j] = fmaf(xl[j][d], w, a[j]);
        }
        #pragma unroll
        for (int j = 0; j < 8; ++j) {
            float sq = a[j] * a[j];
            #pragma unroll
            for (int off = 16; off > 0; off >>= 1) sq += __shfl_xor(sq, off, 64);
            ks[(tb + j) * HS + s] = f2bf(a[j]);
            if (s == 0) kt[tb + j] = sqrtf(INV_CURV + sq);
        }
    }
    // ---- V -> v_tan (logmap0), stored transposed bf16 [bh][d=s][n] ----
    {
        const float* W = Wv + (size_t)h * SD * HS + s;
        float a[8];
        const float bias = bv[h * HS + s];
        #pragma unroll
        for (int j = 0; j < 8; ++j) a[j] = bias;
        for (int d = 0; d < SD; ++d) {
            const float w = W[(size_t)d * HS];
            #pragma unroll
            for (int j = 0; j < 8; ++j) a[j] = fmaf(xl[j][d], w, a[j]);
        }
        uintT pk[4];
        #pragma unroll
        for (int j = 0; j < 8; j += 2) {
            float vt2[2];
            #pragma unroll
            for (int e = 0; e < 2; ++e) {
                const float av = a[j + e];
                float sq = av * av;
                #pragma unroll
                for (int off = 16; off > 0; off >>= 1) sq += __shfl_xor(sq, off, 64);
                const float vtime = sqrtf(INV_CURV + sq);
                const float xn    = sqrtf(fmaxf(sq, EPSF));
                const float z     = fmaxf(vtime / RCONST, 1.0f + 1e-7f);
                const float dd    = RCONST * logf(z + sqrtf(z * z - 1.0f));
                vt2[e] = (dd / xn) * av;
            }
            pk[j >> 1] = packbf(vt2[0], vt2[1]);
        }
        uint4 w4; w4.x = pk[0]; w4.y = pk[1]; w4.z = pk[2]; w4.w = pk[3];
        *(uint4*)(vtT + ((size_t)bh * HS + s) * NN + n0) = w4;
    }
}

// ---------------------------------------------------------------------------
// Kernel 2: MFMA flash attention. 4 waves/block, 16 queries/wave, KV tile 32.
// Swapped QK^T (A=K, B=Q): lane holds query l&15, keys 4*(l>>4)+r.
// Fixed softmax max M0 (Lorentz bound): streaming sum, no rescale.
// ---------------------------------------------------------------------------
__global__ __launch_bounds__(256) void attn_mfma(
    const ushortT* __restrict__ qs, const float* __restrict__ qt,
    const ushortT* __restrict__ ks, const float* __restrict__ kt,
    const ushortT* __restrict__ vtT, float* __restrict__ cat)
{
    const int bh   = blockIdx.x >> 5;
    const int qblk = blockIdx.x & 31;
    const int wid  = threadIdx.x >> 6;
    const int lane = threadIdx.x & 63;
    const int g = lane >> 4, q = lane & 15;
    const int qb = qblk * 64 + wid * 16;

    const size_t bhNN = (size_t)bh * NN;
    U4 qf; qf.u = *(const uint4*)(qs + (bhNN + qb + q) * HS + 8 * g);
    const float qts = qt[bhNN + qb + q] * SCALE;

    f32x4 acc0 = {0.f, 0.f, 0.f, 0.f};
    f32x4 acc1 = {0.f, 0.f, 0.f, 0.f};
    float sum = 0.f;

    const ushortT* kp  = ks  + bhNN * HS;
    const float*   ktp = kt  + bhNN;
    const ushortT* vp  = vtT + bhNN * HS;   // [32 d][NN]

    const int sA = ((2 * g) & 3) * 16 + q;
    const int sB = ((2 * g + 1) & 3) * 16 + q;
    const bool hi = (g >= 2);

    for (int t = 0; t < NN; t += 32) {
        U4 k0, k1;
        k0.u = *(const uint4*)(kp + (size_t)(t + q) * HS + 8 * g);
        k1.u = *(const uint4*)(kp + (size_t)(t + 16 + q) * HS + 8 * g);
        const f32x4 z = {0.f, 0.f, 0.f, 0.f};
        f32x4 s0 = __builtin_amdgcn_mfma_f32_16x16x32_bf16(k0.h, qf.h, z, 0, 0, 0);
        f32x4 s1 = __builtin_amdgcn_mfma_f32_16x16x32_bf16(k1.h, qf.h, z, 0, 0, 0);
        const float4 kt0 = *(const float4*)(ktp + t + 4 * g);
        const float4 kt1 = *(const float4*)(ktp + t + 16 + 4 * g);

        float p0[4], p1[4];
        const float kt0a[4] = {kt0.x, kt0.y, kt0.z, kt0.w};
        const float kt1a[4] = {kt1.x, kt1.y, kt1.z, kt1.w};
        #pragma unroll
        for (int r = 0; r < 4; ++r) {
            p0[r] = __expf(fmaf(s0[r], SCALE, fmaf(-qts, kt0a[r], M0NEG)));
            p1[r] = __expf(fmaf(s1[r], SCALE, fmaf(-qts, kt1a[r], M0NEG)));
            sum += p0[r] + p1[r];
        }
        const uintT pk0 = packbf(p0[0], p0[1]);
        const uintT pk1 = packbf(p0[2], p0[3]);
        const uintT pk2 = packbf(p1[0], p1[1]);
        const uintT pk3 = packbf(p1[2], p1[3]);

        const uintT a0 = __shfl(pk0, sA, 64), b0 = __shfl(pk2, sA, 64);
        const uintT a1 = __shfl(pk1, sA, 64), b1 = __shfl(pk3, sA, 64);
        const uintT a2 = __shfl(pk0, sB, 64), b2 = __shfl(pk2, sB, 64);
        const uintT a3 = __shfl(pk1, sB, 64), b3 = __shfl(pk3, sB, 64);
        U4 pf;
        pf.u.x = hi ? b0 : a0;
        pf.u.y = hi ? b1 : a1;
        pf.u.z = hi ? b2 : a2;
        pf.u.w = hi ? b3 : a3;

        U4 v0, v1;
        v0.u = *(const uint4*)(vp + (size_t)q * NN + t + 8 * g);
        v1.u = *(const uint4*)(vp + (size_t)(16 + q) * NN + t + 8 * g);
        acc0 = __builtin_amdgcn_mfma_f32_16x16x32_bf16(pf.h, v0.h, acc0, 0, 0, 0);
        acc1 = __builtin_amdgcn_mfma_f32_16x16x32_bf16(pf.h, v1.h, acc1, 0, 0, 0);
    }

    // full per-query sum (query = l&15 after group reduce)
    sum += __shfl_xor(sum, 16, 64);
    sum += __shfl_xor(sum, 32, 64);

    const int b = bh >> 3, h = bh & 7;
    #pragma unroll
    for (int r = 0; r < 4; ++r) {
        const float sr  = __shfl(sum, 4 * g + r, 64);
        const float inv = 1.0f / sr;
        const float t0 = acc0[r] * inv;
        const float t1 = acc1[r] * inv;
        float un2 = t0 * t0 + t1 * t1;
        #pragma unroll
        for (int off = 8; off > 0; off >>= 1) un2 += __shfl_xor(un2, off, 64);
        const float un  = sqrtf(fmaxf(un2, 1e-18f));
        const float fac = RCONST * sinhf(un / RCONST) / un;
        const int n = qb + 4 * g + r;
        float* cp = cat + ((size_t)(b * NN + n)) * SS + h * HS;
        cp[q]      = fac * t0;
        cp[16 + q] = fac * t1;
    }
}

// ---------------------------------------------------------------------------
// Kernel 3: output Lorentz FC, 8 tokens per block.
// ---------------------------------------------------------------------------
__global__ __launch_bounds__(256) void out_kernel(
    const float* __restrict__ cat, const float* __restrict__ Wo,
    const float* __restrict__ bo, float* __restrict__ out)
{
    __shared__ float row[8][SS];
    __shared__ float red0[8][4];
    __shared__ float red1[8][4];
    const int bn0 = blockIdx.x * 8;
    const int tid = threadIdx.x;
    const int wave = tid >> 6, lane = tid & 63;

    #pragma unroll
    for (int j = 0; j < 8; ++j) {
        const float v = cat[(size_t)(bn0 + j) * SS + tid];
        row[j][tid] = v;
        float sq = v * v;
        #pragma unroll
        for (int off = 32; off > 0; off >>= 1) sq += __shfl_xor(sq, off, 64);
        if (lane == 0) red0[j][wave] = sq;
    }
    __syncthreads();

    float a[8];
    const float bos = bo[tid];
    const float w0  = Wo[tid];
    #pragma unroll
    for (int j = 0; j < 8; ++j) {
        const float tin = sqrtf(INV_CURV + red0[j][0] + red0[j][1] + red0[j][2] + red0[j][3]);
        a[j] = fmaf(tin, w0, bos);
    }
    const float* Wp = Wo + SS + tid;
    for (int d = 0; d < SS; ++d) {
        const float w = Wp[(size_t)d * SS];
        #pragma unroll
        for (int j = 0; j < 8; ++j) a[j] = fmaf(row[j][d], w, a[j]);
    }
    #pragma unroll
    for (int j = 0; j < 8; ++j) {
        float sq = a[j] * a[j];
        #pragma unroll
        for (int off = 32; off > 0; off >>= 1) sq += __shfl_xor(sq, off, 64);
        if (lane == 0) red1[j][wave] = sq;
        out[(size_t)(bn0 + j) * SD + 1 + tid] = a[j];
    }
    __syncthreads();
    if (tid < 8) {
        const int j = tid;
        const float ys = red1[j][0] + red1[j][1] + red1[j][2] + red1[j][3];
        out[(size_t)(bn0 + j) * SD] = sqrtf(INV_CURV + ys);
    }
}

// ---------------------------------------------------------------------------
extern "C" void kernel_launch(void* const* d_in, const int* in_sizes, int n_in,
                              void* d_out, int out_size, void* d_ws, size_t ws_size,
                              hipStream_t stream)
{
    const float* x  = (const float*)d_in[0];
    const float* Wq = (const float*)d_in[1];
    const float* bq = (const float*)d_in[2];
    const float* Wk = (const float*)d_in[3];
    const float* bk = (const float*)d_in[4];
    const float* Wv = (const float*)d_in[5];
    const float* bv = (const float*)d_in[6];
    const float* Wo = (const float*)d_in[7];
    const float* bo = (const float*)d_in[8];
    float* out = (float*)d_out;

    char* w = (char*)d_ws;
    ushortT* qs  = (ushortT*)(w);                               // 4 MB
    ushortT* ks  = (ushortT*)(w + ((size_t)4 << 20));           // 4 MB
    ushortT* vtT = (ushortT*)(w + ((size_t)8 << 20));           // 4 MB
    float*   qt  = (float*)(w + ((size_t)12 << 20));            // 256 KB
    float*   kt  = (float*)(w + ((size_t)12 << 20) + (256 << 10)); // 256 KB
    float*   cat = (float*)(w + ((size_t)13 << 20));            // 8 MB

    proj_kernel<<<BB * NN / 8, 256, 0, stream>>>(x, Wq, bq, Wk, bk, Wv, bv,
                                                 qs, qt, ks, kt, vtT);
    attn_mfma<<<BB * NH * NN / 64, 256, 0, stream>>>(qs, qt, ks, kt, vtT, cat);
    out_kernel<<<BB * NN / 8, 256, 0, stream>>>(cat, Wo, bo, out);
}

// Round 4
// 174.128 us; speedup vs baseline: 9.7628x; 1.4418x over previous
//
#include <hip/hip_runtime.h>
#include <hip/hip_bf16.h>
#include <math.h>

#define NH 8
#define HS 32
#define SD 257
#define SS 256
#define NN 2048
#define BB 4
#define INV_CURV 10.0f
#define RCONST 3.16227766016837933f
#define SCALE 0.17677669529663687f
#define M0NEG 1.76776695296636881f   // -score_upper_bound = (1/CURV)*SCALE
#define EPSF 1e-9f

typedef unsigned short ushortT;
typedef unsigned int uintT;
typedef __attribute__((ext_vector_type(8))) short bf16x8;
typedef __attribute__((ext_vector_type(4))) float f32x4;

union U4 { uint4 u; bf16x8 h; };

__device__ inline ushortT f2bf(float f) {
    __hip_bfloat16 h = __float2bfloat16(f);
    return *(ushortT*)&h;
}
__device__ inline uintT packbf(float a, float b) {
    return (uintT)f2bf(a) | ((uintT)f2bf(b) << 16);
}

// ---------------------------------------------------------------------------
// Prep: xbf[n][256] = bf16(x[n][1..256]); WT[m*256+h*32+s][dk] = W_m[h][dk+1][s]
// ---------------------------------------------------------------------------
__global__ __launch_bounds__(256) void prep_kernel(
    const float* __restrict__ x,
    const float* __restrict__ Wq, const float* __restrict__ Wk,
    const float* __restrict__ Wv,
    ushortT* __restrict__ xbf, ushortT* __restrict__ WT)
{
    const int b = blockIdx.x, tid = threadIdx.x;
    if (b < 1024) {
        const int tok = b * 8 + (tid >> 5);
        const int c   = (tid & 31) * 8;
        const float* src = x + (size_t)tok * SD + 1 + c;
        uint4 w4;
        w4.x = packbf(src[0], src[1]);
        w4.y = packbf(src[2], src[3]);
        w4.z = packbf(src[4], src[5]);
        w4.w = packbf(src[6], src[7]);
        *(uint4*)(xbf + (size_t)tok * 256 + c) = w4;
    } else {
        const int row = (b - 1024) * 8 + (tid >> 5);
        const int dk  = (tid & 31) * 8;
        const int m = row >> 8, h = (row >> 5) & 7, s = row & 31;
        const float* Wsrc = (m == 0 ? Wq : (m == 1 ? Wk : Wv)) + (size_t)h * SD * HS + s;
        uint4 w4;
        w4.x = packbf(Wsrc[(size_t)(dk + 1) * HS], Wsrc[(size_t)(dk + 2) * HS]);
        w4.y = packbf(Wsrc[(size_t)(dk + 3) * HS], Wsrc[(size_t)(dk + 4) * HS]);
        w4.z = packbf(Wsrc[(size_t)(dk + 5) * HS], Wsrc[(size_t)(dk + 6) * HS]);
        w4.w = packbf(Wsrc[(size_t)(dk + 7) * HS], Wsrc[(size_t)(dk + 8) * HS]);
        *(uint4*)(WT + (size_t)row * 256 + dk) = w4;
    }
}

// ---------------------------------------------------------------------------
// Proj via MFMA — UNIFIED path for q/k/v: D[s][tok] = Wt_frag x xbf_frag.
// Block = 16 tokens, 4 waves; wave w handles mats 6w..6w+5 (mat = m*8+h).
// K=256 MFMA + fp32 rank-1 (time col) + bias; ns reduced over s per token.
// v: logmap0 epilogue (fac per token), transposed scalar stores to vtT[d][n].
// ---------------------------------------------------------------------------
__global__ __launch_bounds__(256) void proj_mfma(
    const float* __restrict__ x, const ushortT* __restrict__ xbf,
    const ushortT* __restrict__ WT,
    const float* __restrict__ Wq, const float* __restrict__ Wk,
    const float* __restrict__ Wv,
    const float* __restrict__ bq, const float* __restrict__ bk,
    const float* __restrict__ bv,
    ushortT* __restrict__ qs, float* __restrict__ qt,
    ushortT* __restrict__ ks, float* __restrict__ kt,
    ushortT* __restrict__ vtT)
{
    const int tok0 = blockIdx.x * 16;
    const int w = threadIdx.x >> 6, lane = threadIdx.x & 63;
    const int g = lane >> 4, c = lane & 15;
    const int b = tok0 >> 11, n0 = tok0 & (NN - 1);

    U4 xf[8];
    const ushortT* xr = xbf + (size_t)(tok0 + c) * 256 + 8 * g;
    #pragma unroll
    for (int k = 0; k < 8; ++k) xf[k].u = *(const uint4*)(xr + 32 * k);
    const float xt1 = x[(size_t)(tok0 + c) * SD];

    for (int i = 0; i < 6; ++i) {
        const int mt = w * 6 + i;
        const int m = mt >> 3, h = mt & 7;
        const ushortT* Wb = WT + (size_t)mt * 32 * 256;
        const float* Wsrc = (m == 0 ? Wq : (m == 1 ? Wk : Wv)) + (size_t)h * SD * HS;
        const float* bsrc = (m == 0 ? bq : (m == 1 ? bk : bv)) + h * HS;

        f32x4 a0 = {0.f,0.f,0.f,0.f}, a1 = {0.f,0.f,0.f,0.f};
        #pragma unroll
        for (int k = 0; k < 8; ++k) {
            U4 A0, A1;
            A0.u = *(const uint4*)(Wb + (size_t)c * 256 + 32 * k + 8 * g);
            A1.u = *(const uint4*)(Wb + (size_t)(16 + c) * 256 + 32 * k + 8 * g);
            a0 = __builtin_amdgcn_mfma_f32_16x16x32_bf16(A0.h, xf[k].h, a0, 0, 0, 0);
            a1 = __builtin_amdgcn_mfma_f32_16x16x32_bf16(A1.h, xf[k].h, a1, 0, 0, 0);
        }
        // a0[r] = space[tok=c][s=4g+r], a1[r] = space[tok=c][s=16+4g+r]
        float ns = 0.f;
        #pragma unroll
        for (int r = 0; r < 4; ++r) {
            a0[r] = fmaf(Wsrc[4 * g + r], xt1, a0[r]) + bsrc[4 * g + r];
            a1[r] = fmaf(Wsrc[16 + 4 * g + r], xt1, a1[r]) + bsrc[16 + 4 * g + r];
            ns += a0[r] * a0[r] + a1[r] * a1[r];
        }
        ns += __shfl_xor(ns, 16, 64);
        ns += __shfl_xor(ns, 32, 64);   // full |space|^2 of token c

        if (m < 2) {
            const size_t tb = (size_t)(b * NH + h) * NN + n0 + c;
            float*   tdst = (m == 0 ? qt : kt);
            ushortT* sdst = (m == 0 ? qs : ks);
            if (lane < 16) tdst[tb] = sqrtf(INV_CURV + ns);
            uint2 u0, u1;
            u0.x = packbf(a0[0], a0[1]); u0.y = packbf(a0[2], a0[3]);
            u1.x = packbf(a1[0], a1[1]); u1.y = packbf(a1[2], a1[3]);
            *(uint2*)(sdst + tb * HS + 4 * g) = u0;
            *(uint2*)(sdst + tb * HS + 16 + 4 * g) = u1;
        } else {
            const float vtime = sqrtf(INV_CURV + ns);
            const float xn  = sqrtf(fmaxf(ns, EPSF));
            const float z   = fmaxf(vtime / RCONST, 1.0f + 1e-7f);
            const float dd  = RCONST * logf(z + sqrtf(z * z - 1.0f));
            const float fac = dd / xn;
            const size_t vb = (size_t)(b * NH + h) * HS;
            #pragma unroll
            for (int r = 0; r < 4; ++r) {
                vtT[(vb + 4 * g + r) * NN + n0 + c]      = f2bf(fac * a0[r]);
                vtT[(vb + 16 + 4 * g + r) * NN + n0 + c] = f2bf(fac * a1[r]);
            }
        }
    }
}

// ---------------------------------------------------------------------------
// Kernel 2: MFMA flash attention — EXACT round-2 version (fp32 cat out).
// ---------------------------------------------------------------------------
__global__ __launch_bounds__(256) void attn_mfma(
    const ushortT* __restrict__ qs, const float* __restrict__ qt,
    const ushortT* __restrict__ ks, const float* __restrict__ kt,
    const ushortT* __restrict__ vtT, float* __restrict__ cat)
{
    const int bh   = blockIdx.x >> 5;
    const int qblk = blockIdx.x & 31;
    const int wid  = threadIdx.x >> 6;
    const int lane = threadIdx.x & 63;
    const int g = lane >> 4, q = lane & 15;
    const int qb = qblk * 64 + wid * 16;

    const size_t bhNN = (size_t)bh * NN;
    U4 qf; qf.u = *(const uint4*)(qs + (bhNN + qb + q) * HS + 8 * g);
    const float qts = qt[bhNN + qb + q] * SCALE;

    f32x4 acc0 = {0.f, 0.f, 0.f, 0.f};
    f32x4 acc1 = {0.f, 0.f, 0.f, 0.f};
    float sum = 0.f;

    const ushortT* kp  = ks  + bhNN * HS;
    const float*   ktp = kt  + bhNN;
    const ushortT* vp  = vtT + bhNN * HS;

    const int sA = ((2 * g) & 3) * 16 + q;
    const int sB = ((2 * g + 1) & 3) * 16 + q;
    const bool hi = (g >= 2);

    for (int t = 0; t < NN; t += 32) {
        U4 k0, k1;
        k0.u = *(const uint4*)(kp + (size_t)(t + q) * HS + 8 * g);
        k1.u = *(const uint4*)(kp + (size_t)(t + 16 + q) * HS + 8 * g);
        const f32x4 z = {0.f, 0.f, 0.f, 0.f};
        f32x4 s0 = __builtin_amdgcn_mfma_f32_16x16x32_bf16(k0.h, qf.h, z, 0, 0, 0);
        f32x4 s1 = __builtin_amdgcn_mfma_f32_16x16x32_bf16(k1.h, qf.h, z, 0, 0, 0);
        const float4 kt0 = *(const float4*)(ktp + t + 4 * g);
        const float4 kt1 = *(const float4*)(ktp + t + 16 + 4 * g);

        float p0[4], p1[4];
        const float kt0a[4] = {kt0.x, kt0.y, kt0.z, kt0.w};
        const float kt1a[4] = {kt1.x, kt1.y, kt1.z, kt1.w};
        #pragma unroll
        for (int r = 0; r < 4; ++r) {
            p0[r] = __expf(fmaf(s0[r], SCALE, fmaf(-qts, kt0a[r], M0NEG)));
            p1[r] = __expf(fmaf(s1[r], SCALE, fmaf(-qts, kt1a[r], M0NEG)));
            sum += p0[r] + p1[r];
        }
        const uintT pk0 = packbf(p0[0], p0[1]);
        const uintT pk1 = packbf(p0[2], p0[3]);
        const uintT pk2 = packbf(p1[0], p1[1]);
        const uintT pk3 = packbf(p1[2], p1[3]);

        const uintT a0 = __shfl(pk0, sA, 64), b0 = __shfl(pk2, sA, 64);
        const uintT a1 = __shfl(pk1, sA, 64), b1 = __shfl(pk3, sA, 64);
        const uintT a2 = __shfl(pk0, sB, 64), b2 = __shfl(pk2, sB, 64);
        const uintT a3 = __shfl(pk1, sB, 64), b3 = __shfl(pk3, sB, 64);
        U4 pf;
        pf.u.x = hi ? b0 : a0;
        pf.u.y = hi ? b1 : a1;
        pf.u.z = hi ? b2 : a2;
        pf.u.w = hi ? b3 : a3;

        U4 v0, v1;
        v0.u = *(const uint4*)(vp + (size_t)q * NN + t + 8 * g);
        v1.u = *(const uint4*)(vp + (size_t)(16 + q) * NN + t + 8 * g);
        acc0 = __builtin_amdgcn_mfma_f32_16x16x32_bf16(pf.h, v0.h, acc0, 0, 0, 0);
        acc1 = __builtin_amdgcn_mfma_f32_16x16x32_bf16(pf.h, v1.h, acc1, 0, 0, 0);
    }

    sum += __shfl_xor(sum, 16, 64);
    sum += __shfl_xor(sum, 32, 64);

    const int b = bh >> 3, h = bh & 7;
    #pragma unroll
    for (int r = 0; r < 4; ++r) {
        const float sr  = __shfl(sum, 4 * g + r, 64);
        const float inv = 1.0f / sr;
        const float t0 = acc0[r] * inv;
        const float t1 = acc1[r] * inv;
        float un2 = t0 * t0 + t1 * t1;
        #pragma unroll
        for (int off = 8; off > 0; off >>= 1) un2 += __shfl_xor(un2, off, 64);
        const float un  = sqrtf(fmaxf(un2, 1e-18f));
        const float fac = RCONST * sinhf(un / RCONST) / un;
        const int n = qb + 4 * g + r;
        float* cp = cat + ((size_t)(b * NN + n)) * SS + h * HS;
        cp[q]      = fac * t0;
        cp[16 + q] = fac * t1;
    }
}

// ---------------------------------------------------------------------------
// Kernel 3: output Lorentz FC — EXACT round-2 scalar version, 8 tokens/block.
// ---------------------------------------------------------------------------
__global__ __launch_bounds__(256) void out_kernel(
    const float* __restrict__ cat, const float* __restrict__ Wo,
    const float* __restrict__ bo, float* __restrict__ out)
{
    __shared__ float row[8][SS];
    __shared__ float red0[8][4];
    __shared__ float red1[8][4];
    const int bn0 = blockIdx.x * 8;
    const int tid = threadIdx.x;
    const int wave = tid >> 6, lane = tid & 63;

    #pragma unroll
    for (int j = 0; j < 8; ++j) {
        const float v = cat[(size_t)(bn0 + j) * SS + tid];
        row[j][tid] = v;
        float sq = v * v;
        #pragma unroll
        for (int off = 32; off > 0; off >>= 1) sq += __shfl_xor(sq, off, 64);
        if (lane == 0) red0[j][wave] = sq;
    }
    __syncthreads();

    float a[8];
    const float bos = bo[tid];
    const float w0  = Wo[tid];
    #pragma unroll
    for (int j = 0; j < 8; ++j) {
        const float tin = sqrtf(INV_CURV + red0[j][0] + red0[j][1] + red0[j][2] + red0[j][3]);
        a[j] = fmaf(tin, w0, bos);
    }
    const float* Wp = Wo + SS + tid;
    for (int d = 0; d < SS; ++d) {
        const float w = Wp[(size_t)d * SS];
        #pragma unroll
        for (int j = 0; j < 8; ++j) a[j] = fmaf(row[j][d], w, a[j]);
    }
    #pragma unroll
    for (int j = 0; j < 8; ++j) {
        float sq = a[j] * a[j];
        #pragma unroll
        for (int off = 32; off > 0; off >>= 1) sq += __shfl_xor(sq, off, 64);
        if (lane == 0) red1[j][wave] = sq;
        out[(size_t)(bn0 + j) * SD + 1 + tid] = a[j];
    }
    __syncthreads();
    if (tid < 8) {
        const int j = tid;
        const float ys = red1[j][0] + red1[j][1] + red1[j][2] + red1[j][3];
        out[(size_t)(bn0 + j) * SD] = sqrtf(INV_CURV + ys);
    }
}

// ---------------------------------------------------------------------------
extern "C" void kernel_launch(void* const* d_in, const int* in_sizes, int n_in,
                              void* d_out, int out_size, void* d_ws, size_t ws_size,
                              hipStream_t stream)
{
    const float* x  = (const float*)d_in[0];
    const float* Wq = (const float*)d_in[1];
    const float* bq = (const float*)d_in[2];
    const float* Wk = (const float*)d_in[3];
    const float* bk = (const float*)d_in[4];
    const float* Wv = (const float*)d_in[5];
    const float* bv = (const float*)d_in[6];
    const float* Wo = (const float*)d_in[7];
    const float* bo = (const float*)d_in[8];
    float* out = (float*)d_out;

    char* w = (char*)d_ws;
    ushortT* xbf = (ushortT*)(w);                         // 4 MB
    ushortT* qs  = (ushortT*)(w + (size_t)4194304);       // 4 MB
    ushortT* ks  = (ushortT*)(w + (size_t)8388608);       // 4 MB
    ushortT* vtT = (ushortT*)(w + (size_t)12582912);      // 4 MB
    float*   cat = (float*)  (w + (size_t)16777216);      // 8 MB fp32
    ushortT* WT  = (ushortT*)(w + (size_t)25165824);      // 384 KB
    float*   qt  = (float*)  (w + (size_t)25559040);      // 256 KB
    float*   kt  = (float*)  (w + (size_t)25821184);      // 256 KB

    prep_kernel<<<1120, 256, 0, stream>>>(x, Wq, Wk, Wv, xbf, WT);
    proj_mfma<<<BB * NN / 16, 256, 0, stream>>>(x, xbf, WT, Wq, Wk, Wv,
                                                bq, bk, bv, qs, qt, ks, kt, vtT);
    attn_mfma<<<BB * NH * NN / 64, 256, 0, stream>>>(qs, qt, ks, kt, vtT, cat);
    out_kernel<<<BB * NN / 8, 256, 0, stream>>>(cat, Wo, bo, out);
}